// Round 16
// baseline (84.291 us; speedup 1.0000x reference)
//
#include <hip/hip_runtime.h>

#define K 5
#define KK (K * K)
#define N_ 8
#define C_ 256
#define H_ 64
#define W_ 64
#define HW (H_ * W_)
#define HO 128
#define WO 128
#define HOWO (HO * WO)
#define HB 4              // base rows per block (full width)
#define CCHUNK 32         // channels per block

typedef __attribute__((ext_vector_type(2))) float f2;

__global__ __launch_bounds__(256)
void carafe_direct_kernel(const float* __restrict__ feat,
                          const float* __restrict__ mask,
                          float* __restrict__ out) {
    const int ht = blockIdx.x;       // 0..15
    const int zc = blockIdx.y;       // 0..63 (n*8 + chunk)
    const int n  = zc >> 3;
    const int c0 = (zc & 7) * CCHUNK;
    const int h0 = ht * HB;

    const int tid = threadIdx.x;
    const int r   = tid >> 6;        // 0..3  base row (one wave = one row)
    const int c   = tid & 63;        // 0..63 base col (full width)
    const int hb  = h0 + r;

    // Channel-invariant masks for this thread's 2x2 output quad (f2 over b).
    // OOB taps are folded HERE: mask=0 and the (clamped-address) feature
    // load's garbage value contributes nothing. Inner loop stays pure.
    f2 m0[KK], m1[KK];
    {
        const f2* mb = (const f2*)(mask + (size_t)n * KK * HOWO
                                        + (size_t)(2 * hb) * WO + 2 * c);
        #pragma unroll
        for (int i = 0; i < KK; ++i) {
            m0[i] = mb[(size_t)i * (HOWO / 2)];            // a = 0
            m1[i] = mb[(size_t)i * (HOWO / 2) + WO / 2];   // a = 1
        }
        #pragma unroll
        for (int ki = 0; ki < K; ++ki) {
            bool vr = (hb - 2 + ki >= 0) && (hb - 2 + ki < H_);
            #pragma unroll
            for (int kj = 0; kj < K; ++kj) {
                bool vc = (c - 2 + kj >= 0) && (c - 2 + kj < W_);
                if (!(vr && vc)) { m0[ki * K + kj] = (f2)0.f; m1[ki * K + kj] = (f2)0.f; }
            }
        }
    }

    // Clamped tap offsets (element index into a channel plane), 25 VGPRs.
    int off[KK];
    #pragma unroll
    for (int ki = 0; ki < K; ++ki) {
        int hs = hb - 2 + ki; hs = hs < 0 ? 0 : (hs > H_ - 1 ? H_ - 1 : hs);
        #pragma unroll
        for (int kj = 0; kj < K; ++kj) {
            int ws = c - 2 + kj; ws = ws < 0 ? 0 : (ws > W_ - 1 ? W_ - 1 : ws);
            off[ki * K + kj] = hs * W_ + ws;
        }
    }

    const float* fbase = feat + (size_t)n * C_ * HW;
    float*       obase = out  + (size_t)n * C_ * HOWO
                              + (size_t)(2 * hb) * WO + 2 * c;

    // Direct-from-global taps: the 2KB/channel halo is L1-resident and
    // shared across the block's waves via L1/L2 (no LDS, no barriers —
    // staging removal per m169/m177: don't stage what cache-fits).
    auto load_ch = [&](float* v, int cc) {
        const float* fp = fbase + (size_t)cc * HW;
        #pragma unroll
        for (int i = 0; i < KK; ++i) v[i] = fp[off[i]];
    };
    auto compute_store = [&](const float* v, int cc) {
        f2 a0 = (f2)0.f, a1 = (f2)0.f;
        #pragma unroll
        for (int i = 0; i < KK; ++i) {
            a0 += v[i] * m0[i];
            a1 += v[i] * m1[i];
        }
        f2* op = (f2*)(obase + (size_t)cc * HOWO);
        __builtin_nontemporal_store(a0, op);            // row 2hb
        __builtin_nontemporal_store(a1, op + WO / 2);   // row 2hb+1
    };

    // Channel-pair software pipeline: ~25 independent loads always in
    // flight per wave (ILP covers L1/L2/HBM latency; two static register
    // sets, all indices compile-time -> no scratch, rule #20).
    float va[KK], vb[KK];
    load_ch(va, c0);
    #pragma unroll 1
    for (int cc = c0; cc < c0 + CCHUNK; cc += 2) {
        load_ch(vb, cc + 1);
        compute_store(va, cc);
        if (cc + 2 < c0 + CCHUNK) load_ch(va, cc + 2);
        compute_store(vb, cc + 1);
    }
}

extern "C" void kernel_launch(void* const* d_in, const int* in_sizes, int n_in,
                              void* d_out, int out_size, void* d_ws, size_t ws_size,
                              hipStream_t stream) {
    const float* feat = (const float*)d_in[0];
    const float* mask = (const float*)d_in[1];
    float* out = (float*)d_out;

    dim3 grid(H_ / HB, N_ * (C_ / CCHUNK));  // (16, 64) = 1024 blocks
    dim3 block(256);
    carafe_direct_kernel<<<grid, block, 0, stream>>>(feat, mask, out);
}

// Round 17
// 42.510 us; speedup vs baseline: 1.9829x; 1.9829x over previous
//
#include <hip/hip_runtime.h>

#define K 5
#define N_ 8
#define C_ 256
#define H_ 64
#define W_ 64
#define HW (H_ * W_)
#define HO 128
#define WO 128
#define HOWO (HO * WO)
#define HB 4              // base rows per block (full width)
#define CCHUNK 32         // channels per block
#define UC 8              // channels per stage group (2 float4 slabs)
#define NGROUP (CCHUNK / UC)      // 4
#define LDS_R (HB + K - 1)        // 8 halo rows
#define LDS_C 68                  // 64 cols + 2 pad each side (zero-filled)
#define POS (LDS_R * LDS_C)       // 544

typedef __attribute__((ext_vector_type(2))) float f2;

// Session-best configuration (R9, 42.8us ~ 4.4 TB/s effective):
//  - full-width tiles: every global load/store instruction covers full
//    aligned 256B/512B rows (stream granularity was the real lever)
//  - quad ownership: one thread computes the 2x2 upsample quad, so each
//    25-tap LDS window read serves 4 outputs x 8 channels
//  - depth-1 T14 staging (loads issued before compute, written after)
//  - nontemporal stores (marginally better than cached, R15 A/B)
// Falsified levers (R5-R16): schedule variants, barrier drains, mask
// residency, prefetch depth, occupancy both directions, store type,
// staging removal. Remaining gap to 6.3 TB/s copy is the op's inherent
// mixed-stream + on-chip-pipeline overhead.
__global__ __launch_bounds__(256)
void carafe_row_kernel(const float* __restrict__ feat,
                       const float* __restrict__ mask,
                       float* __restrict__ out) {
    const int ht = blockIdx.x;       // 0..15
    const int zc = blockIdx.y;       // 0..63 (n*8 + chunk)
    const int n  = zc >> 3;
    const int c0 = (zc & 7) * CCHUNK;
    const int h0 = ht * HB;

    const int tid = threadIdx.x;
    const int r   = tid >> 6;        // 0..3  base row (one wave = one row)
    const int c   = tid & 63;        // 0..63 base col (full width)
    const int hb  = h0 + r;

    // Channel-invariant masks for this thread's 2x2 output quad (f2 over b).
    f2 m0[K * K], m1[K * K];
    {
        const f2* mb = (const f2*)(mask + (size_t)n * (K * K) * HOWO
                                        + (size_t)(2 * hb) * WO + 2 * c);
        #pragma unroll
        for (int i = 0; i < K * K; ++i) {
            m0[i] = mb[(size_t)i * (HOWO / 2)];            // a = 0
            m1[i] = mb[(size_t)i * (HOWO / 2) + WO / 2];   // a = 1
        }
    }

    // Staging geometry: halo positions tid, tid+256, tid+512 (if < POS).
    int off[3]; bool val[3];
    #pragma unroll
    for (int i = 0; i < 3; ++i) {
        int p  = tid + i * 256;
        int rr = p / LDS_C, cc = p - rr * LDS_C;
        int hs = h0 - 2 + rr;
        int ws = cc - 2;
        val[i] = (p < POS) && (hs >= 0) && (hs < H_) && (ws >= 0) && (ws < W_);
        off[i] = hs * W_ + ws;
    }

    // Channel-interleaved halo tile: [buf][slab of 4ch][pos] float4. 34816 B.
    __shared__ float4 lds[2][2][POS];

    const float* fbase = feat + (size_t)n * C_ * HW;
    float*       obase = out  + (size_t)n * C_ * HOWO
                              + (size_t)(2 * hb) * WO + 2 * c;

    // Depth-1 staging, single register set, all indices static.
    float sreg[3][UC];
    auto stage_load = [&](int cbase) {
        const float* fp = fbase + (size_t)cbase * HW;
        #pragma unroll
        for (int i = 0; i < 3; ++i)
            #pragma unroll
            for (int u = 0; u < UC; ++u)
                sreg[i][u] = val[i] ? fp[u * HW + off[i]] : 0.f;
    };
    auto stage_write = [&](int buf) {
        #pragma unroll
        for (int i = 0; i < 3; ++i) {
            int p = tid + i * 256;
            if (p < POS) {
                lds[buf][0][p] = make_float4(sreg[i][0], sreg[i][1],
                                             sreg[i][2], sreg[i][3]);
                lds[buf][1][p] = make_float4(sreg[i][4], sreg[i][5],
                                             sreg[i][6], sreg[i][7]);
            }
        }
    };

    stage_load(c0);
    stage_write(0);
    __syncthreads();

    const int rbase = r * LDS_C + c;

    for (int g = 0; g < NGROUP; ++g) {
        const int buf = g & 1;

        // T14: issue next group's global loads before compute.
        if (g + 1 < NGROUP) stage_load(c0 + (g + 1) * UC);

        #pragma unroll
        for (int ss = 0; ss < 2; ++ss) {
            const float4* Ls = &lds[buf][ss][rbase];
            f2 a0[4], a1[4];
            #pragma unroll
            for (int u = 0; u < 4; ++u) { a0[u] = (f2)0.f; a1[u] = (f2)0.f; }
            #pragma unroll
            for (int ki = 0; ki < K; ++ki) {
                #pragma unroll
                for (int kj = 0; kj < K; ++kj) {
                    float4 f  = Ls[ki * LDS_C + kj];   // 1 ds_read_b128 -> 16 FMA
                    f2 w0m = m0[ki * K + kj];
                    f2 w1m = m1[ki * K + kj];
                    a0[0] += f.x * w0m;  a1[0] += f.x * w1m;
                    a0[1] += f.y * w0m;  a1[1] += f.y * w1m;
                    a0[2] += f.z * w0m;  a1[2] += f.z * w1m;
                    a0[3] += f.w * w0m;  a1[3] += f.w * w1m;
                }
            }
            // One wave = one base row: each store covers a full aligned
            // 512B output row; block writes 8 consecutive rows per channel.
            #pragma unroll
            for (int u = 0; u < 4; ++u) {
                f2* op = (f2*)(obase + (size_t)(c0 + g * UC + ss * 4 + u) * HOWO);
                __builtin_nontemporal_store(a0[u], op);            // row 2hb
                __builtin_nontemporal_store(a1[u], op + WO / 2);   // row 2hb+1
            }
        }

        if (g + 1 < NGROUP) {
            stage_write(buf ^ 1);
            __syncthreads();
        }
    }
}

extern "C" void kernel_launch(void* const* d_in, const int* in_sizes, int n_in,
                              void* d_out, int out_size, void* d_ws, size_t ws_size,
                              hipStream_t stream) {
    const float* feat = (const float*)d_in[0];
    const float* mask = (const float*)d_in[1];
    float* out = (float*)d_out;

    dim3 grid(H_ / HB, N_ * (C_ / CCHUNK));  // (16, 64) = 1024 blocks
    dim3 block(256);
    carafe_row_kernel<<<grid, block, 0, stream>>>(feat, mask, out);
}